// Round 7
// baseline (1370.415 us; speedup 1.0000x reference)
//
#include <hip/hip_runtime.h>

#define D 256
#define T 4
#define NS 64

typedef unsigned int uint32;
typedef unsigned long long u64;
typedef short s16x8 __attribute__((ext_vector_type(8)));
typedef float f32x4 __attribute__((ext_vector_type(4)));

// ---- bf16 helpers (manual RNE) --------------------------------------------
__device__ __forceinline__ float bflo(uint32 u) { return __uint_as_float(u << 16); }
__device__ __forceinline__ float bfhi(uint32 u) { return __uint_as_float(u & 0xffff0000u); }
__device__ __forceinline__ unsigned short f2bf(float x) {
    uint32 u = __float_as_uint(x);
    u = u + 0x7FFFu + ((u >> 16) & 1u);
    return (unsigned short)(u >> 16);
}
__device__ __forceinline__ uint32 pack2(float a, float b) {
    return (uint32)f2bf(a) | ((uint32)f2bf(b) << 16);
}
// relu on 2 packed bf16
__device__ __forceinline__ uint32 relu2(uint32 u) {
    uint32 s = u & 0x80008000u;
    uint32 m = ((s >> 15) ^ 0x00010001u) * 0xFFFFu;
    return u & m;
}

// ---------------------------------------------------------------------------
__global__ void zero_kernel(uint32* __restrict__ p, long long n)
{
    long long i = (long long)blockIdx.x * blockDim.x + threadIdx.x;
    long long st = (long long)gridDim.x * blockDim.x;
    for (; i < n; i += st) p[i] = 0u;
}

__global__ void f2bf_kernel(const float* __restrict__ in, unsigned short* __restrict__ out,
                            long long n8)
{
    long long i = (long long)blockIdx.x * blockDim.x + threadIdx.x;
    long long st = (long long)gridDim.x * blockDim.x;
    for (; i < n8; i += st) {
        float4 a = *(const float4*)(in + i * 8);
        float4 b = *(const float4*)(in + i * 8 + 4);
        uint4 o;
        o.x = pack2(a.x, a.y); o.y = pack2(a.z, a.w);
        o.z = pack2(b.x, b.y); o.w = pack2(b.z, b.w);
        *(uint4*)(out + i * 8) = o;
    }
}

// ---------------------------------------------------------------------------
// 6 weight matrices (gcn0, gcn1, lin_w[0..3]) fp32 256x256 -> B-frag-linear bf16
// ---------------------------------------------------------------------------
__global__ void wfrag_kernel(const float* __restrict__ g0, const float* __restrict__ g1,
                             const float* __restrict__ lw, unsigned short* __restrict__ out)
{
    int o = blockIdx.x * 256 + threadIdx.x;   // 0..65535
    int mat = blockIdx.y;
    const float* W = (mat == 0) ? g0 : (mat == 1) ? g1 : (lw + (size_t)(mat - 2) * 65536);
    int j = o & 7, lane = (o >> 3) & 63, ks = (o >> 9) & 7, nt = o >> 12;
    int n15 = lane & 15, quad = lane >> 4;
    int k = ks * 32 + quad * 8 + j;
    int n = nt * 16 + n15;
    out[(size_t)mat * 65536 + o] = f2bf(W[(size_t)k * 256 + n]);
}

// ---------------------------------------------------------------------------
// MFMA GEMM: C(bf16, Mx256) = A(bf16, Mx256) @ W(bf16 frag-linear) + bias.
// RELU_OUT: apply relu before the bf16 pack (pre-relu for next agg).
// grid (nBlk, Z): z offsets Wfrag/bias/C. In-place safe.
// ---------------------------------------------------------------------------
template<int RELU_OUT>
__global__ __launch_bounds__(256, 2)
void gemm_mfma(const unsigned short* __restrict__ A,
               const unsigned short* __restrict__ Wfrag,
               const float* __restrict__ bias,
               unsigned short* __restrict__ Cout,
               int M, int nStripes)
{
    __shared__ unsigned short Asm[64 * 264];
    int t = threadIdx.x, w = t >> 6, lane = t & 63;
    int n15 = lane & 15, quad = lane >> 4;
    int z = blockIdx.y;
    Wfrag += (size_t)z * 65536;
    bias  += (size_t)z * 256;
    Cout  += (size_t)z * (size_t)M * 256;

    s16x8 bfr[4][8];
#pragma unroll
    for (int nt = 0; nt < 4; nt++)
#pragma unroll
        for (int ks = 0; ks < 8; ks++)
            bfr[nt][ks] = *(const s16x8*)(Wfrag +
                (size_t)(((w * 4 + nt) * 8 + ks) * 64 + lane) * 8);

    float bcol[4];
#pragma unroll
    for (int nt = 0; nt < 4; nt++) bcol[nt] = bias[(w * 4 + nt) * 16 + n15];

    for (int s = blockIdx.x; s < nStripes; s += gridDim.x) {
        int m0 = s * 64;
        __syncthreads();
#pragma unroll
        for (int i = 0; i < 8; i++) {
            int idx = i * 256 + t;
            int m = idx >> 5, kc = (idx & 31) * 8;
            int gm = m0 + m;
            uint4 v = make_uint4(0u, 0u, 0u, 0u);
            if (gm < M) v = *(const uint4*)(A + (size_t)gm * 256 + kc);
            *(uint4*)(Asm + m * 264 + kc) = v;
        }
        __syncthreads();

        f32x4 acc[4][4];
#pragma unroll
        for (int rt = 0; rt < 4; rt++)
#pragma unroll
            for (int nt = 0; nt < 4; nt++)
#pragma unroll
                for (int e = 0; e < 4; e++) acc[rt][nt][e] = 0.f;

#pragma unroll
        for (int rt = 0; rt < 4; rt++) {
            int abase = (rt * 16 + n15) * 264 + quad * 8;
#pragma unroll
            for (int ks = 0; ks < 8; ks++) {
                s16x8 a = *(const s16x8*)(Asm + abase + ks * 32);
#pragma unroll
                for (int nt = 0; nt < 4; nt++)
                    acc[rt][nt] = __builtin_amdgcn_mfma_f32_16x16x32_bf16(
                        a, bfr[nt][ks], acc[rt][nt], 0, 0, 0);
            }
        }

#pragma unroll
        for (int rt = 0; rt < 4; rt++) {
            int row0 = m0 + rt * 16 + quad * 4;
#pragma unroll
            for (int nt = 0; nt < 4; nt++) {
                int colp = (w * 4 + nt) * 16 + n15;
#pragma unroll
                for (int r = 0; r < 4; r++) {
                    int gr = row0 + r;
                    if (gr < M) {
                        float v = acc[rt][nt][r] + bcol[nt];
                        if (RELU_OUT) v = fmaxf(v, 0.f);
                        Cout[(size_t)gr * 256 + colp] = f2bf(v);
                    }
                }
            }
        }
    }
}

// ---------------------------------------------------------------------------
__global__ __launch_bounds__(256)
void tinv_kernel(const unsigned short* __restrict__ tr, float* __restrict__ tinv, int rows)
{
    int wave = threadIdx.x >> 6, lane = threadIdx.x & 63;
    int r = blockIdx.x * 4 + wave;
    if (r >= rows) return;
    uint2 q = *(const uint2*)(tr + (size_t)r * D + lane * 4);
    float a = bflo(q.x), b = bfhi(q.x), c = bflo(q.y), d = bfhi(q.y);
    float s = a * a + b * b + c * c + d * d;
#pragma unroll
    for (int off = 32; off; off >>= 1) s += __shfl_xor(s, off);
    if (lane == 0) tinv[r] = 1.f / fmaxf(sqrtf(s), 1e-8f);
}

// ---------------------------------------------------------------------------
// edge counting sort by dst; esorted = (src, dst); eorig = original index
// ---------------------------------------------------------------------------
__global__ void ehist_kernel(const int* __restrict__ dst, int* __restrict__ ecnt, int E)
{
    for (int e = blockIdx.x * blockDim.x + threadIdx.x; e < E;
         e += gridDim.x * blockDim.x)
        atomicAdd(ecnt + dst[e], 1);
}

__global__ void escatter_kernel(const int* __restrict__ src, const int* __restrict__ dst,
                                const int* __restrict__ eptr, int* __restrict__ efill,
                                uint2* __restrict__ esorted, int* __restrict__ eorig, int E)
{
    for (int e = blockIdx.x * blockDim.x + threadIdx.x; e < E;
         e += gridDim.x * blockDim.x) {
        int d = dst[e];
        int pos = eptr[d] + atomicAdd(efill + d, 1);
        esorted[pos] = make_uint2((uint32)src[e], (uint32)d);
        eorig[pos] = e;
    }
}

// ---------------------------------------------------------------------------
// sim via MFMA diagonal: 16 sorted edges per wave; best scattered back to
// ORIGINAL edge order via eorig.
// ---------------------------------------------------------------------------
__global__ __launch_bounds__(256)
void sim3_kernel(const uint2* __restrict__ esorted, const int* __restrict__ eorig,
                 const unsigned short* __restrict__ featb,
                 const unsigned short* __restrict__ tr, const float* __restrict__ tinv,
                 int* __restrict__ bestO, int E, int Nn)
{
    int w = threadIdx.x >> 6, lane = threadIdx.x & 63;
    int n15 = lane & 15, quad = lane >> 4;
    int base = (blockIdx.x * 4 + w) * 16;
    if (base >= E) return;
    int ei = min(base + n15, E - 1);
    uint2 se = esorted[ei];
    const unsigned short* arow = featb + (size_t)se.x * D + quad * 8;
    const unsigned short* brow = tr + (size_t)se.y * D + quad * 8;   // replica 0
    size_t rstride = (size_t)Nn * D;

    f32x4 a0 = {0.f, 0.f, 0.f, 0.f}, a1 = a0, a2 = a0, a3 = a0;
#pragma unroll
    for (int ks = 0; ks < 8; ks++) {
        s16x8 a  = *(const s16x8*)(arow + ks * 32);
        s16x8 b0 = *(const s16x8*)(brow + ks * 32);
        s16x8 b1 = *(const s16x8*)(brow + rstride + ks * 32);
        s16x8 b2 = *(const s16x8*)(brow + 2 * rstride + ks * 32);
        s16x8 b3 = *(const s16x8*)(brow + 3 * rstride + ks * 32);
        a0 = __builtin_amdgcn_mfma_f32_16x16x32_bf16(a, b0, a0, 0, 0, 0);
        a1 = __builtin_amdgcn_mfma_f32_16x16x32_bf16(a, b1, a1, 0, 0, 0);
        a2 = __builtin_amdgcn_mfma_f32_16x16x32_bf16(a, b2, a2, 0, 0, 0);
        a3 = __builtin_amdgcn_mfma_f32_16x16x32_bf16(a, b3, a3, 0, 0, 0);
    }
    if (quad == (n15 >> 2) && base + n15 < E) {
        int r = n15 & 3;
        int d = (int)se.y;
        float v0 = a0[r] * tinv[d];
        float v1 = a1[r] * tinv[Nn + d];
        float v2 = a2[r] * tinv[2 * Nn + d];
        float v3 = a3[r] * tinv[3 * Nn + d];
        float bv = v0; int bi = 0;
        if (v1 > bv) { bv = v1; bi = 1; }   // strict >: first-index ties
        if (v2 > bv) { bv = v2; bi = 2; }
        if (v3 > bv) { bv = v3; bi = 3; }
        bestO[eorig[base + n15]] = bi;
    }
}

// ---------------------------------------------------------------------------
// unified edge list (ORIGINAL order): [0,E) copy1, [E,2E) rewired copy,
// [2E,2E+T*N) identity, then n_total self loops. keep == (weight != 0).
// ---------------------------------------------------------------------------
__device__ __forceinline__ void decode_edge(int e, const int* __restrict__ src,
                                            const int* __restrict__ dst,
                                            const int* __restrict__ bestO,
                                            int E, int Nn, int& s, int& d, bool& keep)
{
    if (e < E) { s = src[e]; d = dst[e]; keep = (s != d); }
    else if (e < 2 * E) {
        int k = e - E; s = src[k]; d = dst[k] + bestO[k] * Nn; keep = (s != d);
    } else if (e < 2 * E + T * Nn) {
        int k = e - 2 * E; int i = k / Nn; int n = k - i * Nn;
        s = n; d = n + i * Nn; keep = (i != 0);
    } else {
        int v = e - (2 * E + T * Nn); s = v; d = v; keep = true;
    }
}

__global__ void hist_kernel(const int* __restrict__ src, const int* __restrict__ dst,
                            const int* __restrict__ bestO, int* __restrict__ cnt,
                            int E, int Nn)
{
    int total = 2 * E + (2 * T + 1) * Nn;
    for (int e = blockIdx.x * blockDim.x + threadIdx.x; e < total;
         e += gridDim.x * blockDim.x) {
        int s, d; bool keep;
        decode_edge(e, src, dst, bestO, E, Nn, s, d, keep);
        if (keep) atomicAdd(cnt + d, 1);
    }
}

__global__ void dinv_kernel(const int* __restrict__ cnt, float* __restrict__ dinv, int n)
{
    int v = blockIdx.x * blockDim.x + threadIdx.x;
    if (v < n) dinv[v] = (cnt[v] > 0) ? rsqrtf((float)cnt[v]) : 0.f;
}

__global__ void scan_sums(const int* __restrict__ cnt, int* __restrict__ aux, int n)
{
    __shared__ int sd[256];
    int idx = blockIdx.x * 256 + threadIdx.x;
    sd[threadIdx.x] = (idx < n) ? cnt[idx] : 0;
    __syncthreads();
    for (int off = 128; off; off >>= 1) {
        if (threadIdx.x < off) sd[threadIdx.x] += sd[threadIdx.x + off];
        __syncthreads();
    }
    if (threadIdx.x == 0) aux[blockIdx.x] = sd[0];
}

__global__ void scan_aux(const int* __restrict__ aux, int* __restrict__ auxex, int nb)
{
    __shared__ int sd[1024];
    int t = threadIdx.x;
    int v = (t < nb) ? aux[t] : 0;
    sd[t] = v;
    __syncthreads();
    for (int off = 1; off < 1024; off <<= 1) {
        int x = (t >= off) ? sd[t - off] : 0;
        __syncthreads();
        sd[t] += x;
        __syncthreads();
    }
    if (t < nb) auxex[t] = sd[t] - v;
}

__global__ void scan_write(const int* __restrict__ cnt, const int* __restrict__ auxex,
                           int* __restrict__ rowptr, int n)
{
    __shared__ int sd[256];
    int t = threadIdx.x;
    int idx = blockIdx.x * 256 + t;
    int v = (idx < n) ? cnt[idx] : 0;
    sd[t] = v;
    __syncthreads();
    for (int off = 1; off < 256; off <<= 1) {
        int x = (t >= off) ? sd[t - off] : 0;
        __syncthreads();
        sd[t] += x;
        __syncthreads();
    }
    if (idx < n) {
        int rp = auxex[blockIdx.x] + sd[t] - v;
        rowptr[idx] = rp;
        if (idx == n - 1) rowptr[n] = rp + v;
    }
}

__global__ void scatter_kernel(const int* __restrict__ src, const int* __restrict__ dst,
                               const int* __restrict__ bestO, const int* __restrict__ rowptr,
                               int* __restrict__ fill, const float* __restrict__ dinv,
                               uint2* __restrict__ colval, int E, int Nn)
{
    int total = 2 * E + (2 * T + 1) * Nn;
    for (int e = blockIdx.x * blockDim.x + threadIdx.x; e < total;
         e += gridDim.x * blockDim.x) {
        int s, d; bool keep;
        decode_edge(e, src, dst, bestO, E, Nn, s, d, keep);
        if (keep) {
            int pos = rowptr[d] + atomicAdd(fill + d, 1);
            colval[pos] = make_uint2((uint32)s, __float_as_uint(dinv[s] * dinv[d]));
        }
    }
}

// ---------------------------------------------------------------------------
// aggregate-first: out[v] = sum_j w_j * (RELU? relu:id)(table[col_j])
// single contiguous bf16 table; NT loads for colval, NT store for output.
// ---------------------------------------------------------------------------
template<int RELU>
__global__ __launch_bounds__(256)
void agg_kernel(const int* __restrict__ rowptr, const uint2* __restrict__ colval,
                const unsigned short* __restrict__ table,
                unsigned short* __restrict__ outb, int n_total)
{
    int wave = threadIdx.x >> 6, lane = threadIdx.x & 63;
    int v = blockIdx.x * 4 + wave;
    if (v >= n_total) return;
    int j0 = rowptr[v], j1 = rowptr[v + 1];
    const unsigned short* tb = table + lane * 4;
    float ax = 0.f, ay = 0.f, az = 0.f, aw = 0.f;
    int j = j0;
    for (; j + 2 <= j1; j += 2) {
        u64 cv0 = __builtin_nontemporal_load((const u64*)(colval + j));
        u64 cv1 = __builtin_nontemporal_load((const u64*)(colval + j + 1));
        uint2 q0 = *(const uint2*)(tb + (size_t)(uint32)cv0 * 256);
        uint2 q1 = *(const uint2*)(tb + (size_t)(uint32)cv1 * 256);
        float w0 = __uint_as_float((uint32)(cv0 >> 32));
        float w1 = __uint_as_float((uint32)(cv1 >> 32));
        if (RELU) { q0.x = relu2(q0.x); q0.y = relu2(q0.y);
                    q1.x = relu2(q1.x); q1.y = relu2(q1.y); }
        ax = fmaf(w0, bflo(q0.x), ax); ay = fmaf(w0, bfhi(q0.x), ay);
        az = fmaf(w0, bflo(q0.y), az); aw = fmaf(w0, bfhi(q0.y), aw);
        ax = fmaf(w1, bflo(q1.x), ax); ay = fmaf(w1, bfhi(q1.x), ay);
        az = fmaf(w1, bflo(q1.y), az); aw = fmaf(w1, bfhi(q1.y), aw);
    }
    if (j < j1) {
        u64 cv0 = __builtin_nontemporal_load((const u64*)(colval + j));
        uint2 q0 = *(const uint2*)(tb + (size_t)(uint32)cv0 * 256);
        float w0 = __uint_as_float((uint32)(cv0 >> 32));
        if (RELU) { q0.x = relu2(q0.x); q0.y = relu2(q0.y); }
        ax = fmaf(w0, bflo(q0.x), ax); ay = fmaf(w0, bfhi(q0.x), ay);
        az = fmaf(w0, bflo(q0.y), az); aw = fmaf(w0, bfhi(q0.y), aw);
    }
    u64 o = (u64)pack2(ax, ay) | ((u64)pack2(az, aw) << 32);
    __builtin_nontemporal_store(o, (u64*)(outb + (size_t)v * D + lane * 4));
}

// ---------------------------------------------------------------------------
// MFMA logits + fused argmax + H
// ---------------------------------------------------------------------------
__global__ __launch_bounds__(256, 2)
void logits_mfma(const unsigned short* __restrict__ af2, const float* __restrict__ Wl,
                 const float* __restrict__ bl, float* __restrict__ H,
                 int M, int Nn, int nStripes)
{
    __shared__ unsigned short Asm[64 * 264];
    int t = threadIdx.x, w = t >> 6, lane = t & 63;
    int n15 = lane & 15, quad = lane >> 4;

    s16x8 bfr[4][8];
#pragma unroll
    for (int nt = 0; nt < 4; nt++)
#pragma unroll
        for (int ks = 0; ks < 8; ks++) {
            s16x8 f;
#pragma unroll
            for (int j = 0; j < 8; j++) {
                int k = ks * 32 + quad * 8 + j;
                f[j] = (short)f2bf(Wl[(size_t)k * NS + nt * 16 + n15]);
            }
            bfr[nt][ks] = f;
        }
    float bcol[4];
#pragma unroll
    for (int nt = 0; nt < 4; nt++) bcol[nt] = bl[nt * 16 + n15];

    for (int s = blockIdx.x; s < nStripes; s += gridDim.x) {
        int m0 = s * 64;
        __syncthreads();
#pragma unroll
        for (int i = 0; i < 8; i++) {
            int idx = i * 256 + t;
            int m = idx >> 5, kc = (idx & 31) * 8;
            int gm = m0 + m;
            uint4 v = make_uint4(0u, 0u, 0u, 0u);
            if (gm < M) {
                v = *(const uint4*)(af2 + (size_t)gm * 256 + kc);
                v.x = relu2(v.x); v.y = relu2(v.y);
                v.z = relu2(v.z); v.w = relu2(v.w);
            }
            *(uint4*)(Asm + m * 264 + kc) = v;
        }
        __syncthreads();

        f32x4 acc[4];
#pragma unroll
        for (int nt = 0; nt < 4; nt++)
#pragma unroll
            for (int e = 0; e < 4; e++) acc[nt][e] = 0.f;

        int abase = (w * 16 + n15) * 264 + quad * 8;
#pragma unroll
        for (int ks = 0; ks < 8; ks++) {
            s16x8 a = *(const s16x8*)(Asm + abase + ks * 32);
#pragma unroll
            for (int nt = 0; nt < 4; nt++)
                acc[nt] = __builtin_amdgcn_mfma_f32_16x16x32_bf16(
                    a, bfr[nt][ks], acc[nt], 0, 0, 0);
        }

#pragma unroll
        for (int e = 0; e < 4; e++) {
            float bv = acc[0][e] + bcol[0]; int bi = n15;
#pragma unroll
            for (int nt = 1; nt < 4; nt++) {
                float v = acc[nt][e] + bcol[nt];
                int c = nt * 16 + n15;
                if (v > bv) { bv = v; bi = c; }
            }
#pragma unroll
            for (int off = 1; off < 16; off <<= 1) {
                float ov = __shfl_xor(bv, off);
                int   oi = __shfl_xor(bi, off);
                if (ov > bv || (ov == bv && oi < bi)) { bv = ov; bi = oi; }
            }
            if (n15 == 0) {
                int gr = m0 + w * 16 + quad * 4 + e;
                if (gr < M) atomicAdd(H + (size_t)(gr % Nn) * NS + bi, 1.0f);
            }
        }
    }
}

// ---------------------------------------------------------------------------
// he[c] = sum_{n: H[n,c]>0} af2[n]
// ---------------------------------------------------------------------------
__global__ __launch_bounds__(64)
void he_kernel(const float* __restrict__ H, const unsigned short* __restrict__ af2,
               float* __restrict__ he, int Nn)
{
    __shared__ float acc[NS * D];   // 64 KiB
    int lane = threadIdx.x;
    for (int i = lane * 4; i < NS * D; i += 256)
        *(float4*)(acc + i) = make_float4(0.f, 0.f, 0.f, 0.f);
    __syncthreads();
    int n0 = blockIdx.x * 128;
    int n1 = min(n0 + 128, Nn);
    for (int n = n0; n < n1; n++) {
        float hv = H[(size_t)n * NS + lane];
        unsigned long long m = __ballot(hv > 0.f);
        if (!m) continue;
        uint2 q = *(const uint2*)(af2 + (size_t)n * D + lane * 4);
        float x0 = bflo(q.x), x1 = bfhi(q.x), x2 = bflo(q.y), x3 = bfhi(q.y);
        while (m) {
            int c = __ffsll(m) - 1;
            m &= m - 1;
            float* p = acc + (size_t)c * D + lane * 4;
            p[0] += x0; p[1] += x1; p[2] += x2; p[3] += x3;
        }
    }
    __syncthreads();
    for (int i = lane; i < NS * D; i += 64) atomicAdd(he + i, acc[i]);
}

// ---------------------------------------------------------------------------
__global__ void bigb_copy(const float* __restrict__ he, float* __restrict__ BigB)
{
    int idx = blockIdx.x * 256 + threadIdx.x;
    if (idx < D * NS) {
        int d = idx >> 6, c = idx & 63;
        BigB[idx] = he[(size_t)c * D + d];
    }
}

__global__ __launch_bounds__(256)
void bigb_mm(const float* __restrict__ lin_w, const float* __restrict__ lin_b,
             const float* __restrict__ he, float* __restrict__ BigB,
             float* __restrict__ beta)
{
    int gw = (int)((blockIdx.x * 256 + threadIdx.x) >> 6);
    int lane = threadIdx.x & 63;
    const int totalA = T * D * NS;
    if (gw >= totalA + T * NS) return;
    const float* xrow; const float* hrow; float* outp;
    if (gw < totalA) {
        int t = gw / (D * NS); int rem = gw - t * D * NS;
        int d = rem / NS; int c = rem - d * NS;
        xrow = lin_w + ((size_t)t * D + d) * D;
        hrow = he + (size_t)c * D;
        outp = BigB + ((size_t)(t + 1) * D + d) * NS + c;
    } else {
        int i = gw - totalA; int t = i / NS; int c = i - t * NS;
        xrow = lin_b + (size_t)t * D;
        hrow = he + (size_t)c * D;
        outp = beta + (size_t)(t + 1) * NS + c;
    }
    float4 x = *(const float4*)(xrow + lane * 4);
    float4 h = *(const float4*)(hrow + lane * 4);
    float s = x.x * h.x + x.y * h.y + x.z * h.z + x.w * h.w;
#pragma unroll
    for (int off = 32; off; off >>= 1) s += __shfl_xor(s, off);
    if (lane == 0) *outp = s;
}

// ---------------------------------------------------------------------------
// MFMA dots: feat(fp32, staged->bf16) @ BigB[rho], grid (nBlk, 5), NT store
// ---------------------------------------------------------------------------
__global__ __launch_bounds__(256, 2)
void dots_mfma(const float* __restrict__ feat, const float* __restrict__ BigB,
               const float* __restrict__ beta, float* __restrict__ dots,
               int Nn, int nStripes)
{
    __shared__ unsigned short Asm[64 * 264];
    int t = threadIdx.x, w = t >> 6, lane = t & 63;
    int n15 = lane & 15, quad = lane >> 4;
    int rho = blockIdx.y;
    const float* Bp = BigB + (size_t)rho * D * NS;

    s16x8 bfr[4][8];
#pragma unroll
    for (int nt = 0; nt < 4; nt++)
#pragma unroll
        for (int ks = 0; ks < 8; ks++) {
            s16x8 f;
#pragma unroll
            for (int j = 0; j < 8; j++) {
                int k = ks * 32 + quad * 8 + j;
                f[j] = (short)f2bf(Bp[(size_t)k * NS + nt * 16 + n15]);
            }
            bfr[nt][ks] = f;
        }
    float bcol[4];
#pragma unroll
    for (int nt = 0; nt < 4; nt++) bcol[nt] = beta[rho * NS + nt * 16 + n15];

    for (int s = blockIdx.x; s < nStripes; s += gridDim.x) {
        int m0 = s * 64;
        __syncthreads();
#pragma unroll
        for (int i = 0; i < 8; i++) {
            int idx = i * 256 + t;
            int m = idx >> 5, kc = (idx & 31) * 8;
            int gm = m0 + m;
            uint4 o = make_uint4(0u, 0u, 0u, 0u);
            if (gm < Nn) {
                float4 a = *(const float4*)(feat + (size_t)gm * 256 + kc);
                float4 b = *(const float4*)(feat + (size_t)gm * 256 + kc + 4);
                o.x = pack2(a.x, a.y); o.y = pack2(a.z, a.w);
                o.z = pack2(b.x, b.y); o.w = pack2(b.z, b.w);
            }
            *(uint4*)(Asm + m * 264 + kc) = o;
        }
        __syncthreads();

        f32x4 acc[4];
#pragma unroll
        for (int nt = 0; nt < 4; nt++)
#pragma unroll
            for (int e = 0; e < 4; e++) acc[nt][e] = 0.f;

        int abase = (w * 16 + n15) * 264 + quad * 8;
#pragma unroll
        for (int ks = 0; ks < 8; ks++) {
            s16x8 a = *(const s16x8*)(Asm + abase + ks * 32);
#pragma unroll
            for (int nt = 0; nt < 4; nt++)
                acc[nt] = __builtin_amdgcn_mfma_f32_16x16x32_bf16(
                    a, bfr[nt][ks], acc[nt], 0, 0, 0);
        }

#pragma unroll
        for (int e = 0; e < 4; e++) {
            int gr = m0 + w * 16 + quad * 4 + e;
            if (gr >= Nn) continue;
#pragma unroll
            for (int nt = 0; nt < 4; nt++) {
                int c = nt * 16 + n15;
                __builtin_nontemporal_store((acc[nt][e] + bcol[nt]) * 0.0625f,
                    dots + ((size_t)rho * Nn + gr) * NS + c);
            }
        }
    }
}

// ---------------------------------------------------------------------------
extern "C" void kernel_launch(void* const* d_in, const int* in_sizes, int n_in,
                              void* d_out, int out_size, void* d_ws, size_t ws_size,
                              hipStream_t stream)
{
    const int*   edge_index = (const int*)d_in[0];
    const float* features   = (const float*)d_in[1];
    const float* lin_w      = (const float*)d_in[2];
    const float* lin_b      = (const float*)d_in[3];
    const float* gcn0_w     = (const float*)d_in[4];
    const float* gcn0_b     = (const float*)d_in[5];
    const float* gcn1_w     = (const float*)d_in[6];
    const float* gcn1_b     = (const float*)d_in[7];
    const float* lin1_w     = (const float*)d_in[8];
    const float* lin1_b     = (const float*)d_in[9];

    int E  = in_sizes[0] / 2;
    int Nn = in_sizes[1] / D;
    int n_total = (T + 1) * Nn;
    int Mrep = T * Nn;
    int colcap = 2 * E + (2 * T + 1) * Nn;

    const int* src = edge_index;
    const int* dst = edge_index + E;

    float* out_H    = (float*)d_out;
    float* out_he   = out_H + (size_t)Nn * NS;
    float* out_dots = out_he + (size_t)NS * D;

    // ---- ws carve: two big bf16 regions + BigB (~256.3 MB)
    char* ws = (char*)d_ws;
    auto carve = [&](size_t bytes) {
        char* p = ws; ws += (bytes + 255) & ~(size_t)255; return p;
    };
    unsigned short* R1   = (unsigned short*)carve((size_t)n_total * D * 2);
    unsigned short* R2   = (unsigned short*)carve((size_t)n_total * D * 2);
    float*          BigB = (float*)carve((size_t)(T + 1) * D * NS * 4);
    float*          beta = (float*)carve((size_t)(T + 1) * NS * 4);
    // R2 layout: [0,Nn) = featb (bf16 features), [Nn,5Nn) = transformed.
    // Contiguous layer-0 gather table = R2. Dies when agg1 overwrites R2.
    unsigned short* featb       = R2;
    unsigned short* transformed = R2 + (size_t)Nn * D;

    // ---- scratch in the out_dots region (dead before dots_mfma overwrites all)
    char* sc = (char*)out_dots;
    auto carve2 = [&](size_t bytes) {
        char* p = sc; sc += (bytes + 255) & ~(size_t)255; return p;
    };
    float* tinv    = (float*)carve2((size_t)Mrep * 4);
    int*   bestO   = (int*)carve2((size_t)E * 4);       // ORIGINAL order
    int*   cnt     = (int*)carve2((size_t)n_total * 4);
    int*   rowptr  = (int*)carve2((size_t)(n_total + 1) * 4);
    int*   fill    = (int*)carve2((size_t)n_total * 4);
    float* dinv    = (float*)carve2((size_t)n_total * 4);
    int*   aux     = (int*)carve2(1024 * 4);
    int*   auxex   = (int*)carve2(1024 * 4);
    uint2* colval  = (uint2*)carve2((size_t)colcap * 8);
    unsigned short* Wfrags = (unsigned short*)carve2((size_t)6 * 65536 * 2);
    int*   ecnt    = (int*)carve2((size_t)Nn * 4);
    int*   eptr    = (int*)carve2((size_t)(Nn + 1) * 4);
    int*   efill   = (int*)carve2((size_t)Nn * 4);
    uint2* esorted = (uint2*)carve2((size_t)E * 8);     // (src, dst) in dst order
    int*   eorig   = (int*)carve2((size_t)E * 4);       // sorted pos -> orig idx

    // ---- zero accumulators
    zero_kernel<<<512, 256, 0, stream>>>((uint32*)cnt, n_total);
    zero_kernel<<<512, 256, 0, stream>>>((uint32*)fill, n_total);
    zero_kernel<<<512, 256, 0, stream>>>((uint32*)ecnt, Nn);
    zero_kernel<<<512, 256, 0, stream>>>((uint32*)efill, Nn);
    zero_kernel<<<512, 256, 0, stream>>>((uint32*)out_H, (long long)Nn * NS + NS * D);
    zero_kernel<<<1, 256, 0, stream>>>((uint32*)beta, (T + 1) * NS);

    // 0. conversions
    wfrag_kernel<<<dim3(256, 6), 256, 0, stream>>>(gcn0_w, gcn1_w, lin_w, Wfrags);
    f2bf_kernel<<<2048, 256, 0, stream>>>(features, featb, (long long)Nn * D / 8);

    // 1. transformed[z] = featb @ lin_w[z] + lin_b[z]  (batched MFMA; reads R2
    //    prefix, writes R2 suffix — disjoint)
    int strN = (Nn + 63) / 64;
    gemm_mfma<0><<<dim3(512, T), 256, 0, stream>>>(featb, Wfrags + 2 * 65536, lin_b,
                                                   transformed, Nn, strN);
    // 2. row norms
    tinv_kernel<<<(Mrep + 3) / 4, 256, 0, stream>>>(transformed, tinv, Mrep);

    // 3. edge sort by dst + MFMA-diagonal sim (best back-scattered to orig order)
    ehist_kernel<<<2048, 256, 0, stream>>>(dst, ecnt, E);
    int enb = (Nn + 255) / 256;
    scan_sums<<<enb, 256, 0, stream>>>(ecnt, aux, Nn);
    scan_aux<<<1, 1024, 0, stream>>>(aux, auxex, enb);
    scan_write<<<enb, 256, 0, stream>>>(ecnt, auxex, eptr, Nn);
    escatter_kernel<<<2048, 256, 0, stream>>>(src, dst, eptr, efill, esorted, eorig, E);
    int nGroups = (E + 15) / 16;
    sim3_kernel<<<(nGroups + 3) / 4, 256, 0, stream>>>(esorted, eorig, featb,
                                                       transformed, tinv, bestO, E, Nn);

    // 4. big-graph CSR (ORIGINAL edge order — no sorted-atomic contention)
    hist_kernel<<<2048, 256, 0, stream>>>(src, dst, bestO, cnt, E, Nn);
    dinv_kernel<<<(n_total + 255) / 256, 256, 0, stream>>>(cnt, dinv, n_total);
    int nb = (n_total + 255) / 256;
    scan_sums<<<nb, 256, 0, stream>>>(cnt, aux, n_total);
    scan_aux<<<1, 1024, 0, stream>>>(aux, auxex, nb);
    scan_write<<<nb, 256, 0, stream>>>(cnt, auxex, rowptr, n_total);
    scatter_kernel<<<2048, 256, 0, stream>>>(src, dst, bestO, rowptr, fill, dinv,
                                             colval, E, Nn);

    // 5. layer 0: agg over contiguous table R2 (relu in-kernel); h=relu(agg@W0+b0)
    int strT = (n_total + 63) / 64;
    agg_kernel<1><<<(n_total + 3) / 4, 256, 0, stream>>>(rowptr, colval, R2, R1, n_total);
    gemm_mfma<1><<<dim3(512, 1), 256, 0, stream>>>(R1, Wfrags, gcn0_b, R1, n_total, strT);

    // 6. layer 1: R1 already relu'd -> agg<0>; af2 = agg@W1+b1 (raw)
    agg_kernel<0><<<(n_total + 3) / 4, 256, 0, stream>>>(rowptr, colval, R1, R2, n_total);
    gemm_mfma<0><<<dim3(512, 1), 256, 0, stream>>>(R2, Wfrags + 65536, gcn1_b, R2,
                                                   n_total, strT);

    // 7. classes + H (MFMA + fused argmax)
    logits_mfma<<<512, 256, 0, stream>>>(R2, lin1_w, lin1_b, out_H, n_total, Nn, strT);

    // 8. hyperedge features
    he_kernel<<<(Nn + 127) / 128, 64, 0, stream>>>(out_H, R2, out_he, Nn);

    // 9. dots (MFMA over 5 rho)
    bigb_copy<<<(D * NS + 255) / 256, 256, 0, stream>>>(out_he, BigB);
    bigb_mm<<<(T * D * NS + T * NS + 3) / 4, 256, 0, stream>>>(lin_w, lin_b, out_he,
                                                               BigB, beta);
    dots_mfma<<<dim3(160, 5), 256, 0, stream>>>(features, BigB, beta, out_dots,
                                                Nn, strN);
}